// Round 1
// baseline (730.048 us; speedup 1.0000x reference)
//
#include <hip/hip_runtime.h>

#define N_NODES 100000
#define N_EDGES 1000000
#define D 64
#define NCLS 10
#define FEAT_BYTES (N_NODES * D * 4)  // 25,600,000 (divisible by 256)

// ---------------------------------------------------------------------------
// Kernel 1: in-degree counts (shared by both layers)
// ---------------------------------------------------------------------------
__global__ __launch_bounds__(256) void count_edges(const int* __restrict__ dst,
                                                   float* __restrict__ cnt) {
    int e = blockIdx.x * blockDim.x + threadIdx.x;
    if (e < N_EDGES) atomicAdd(&cnt[dst[e]], 1.0f);
}

// ---------------------------------------------------------------------------
// Kernel 2: scatter-sum of 64-wide feature rows. One wave per edge:
// lane i handles feature i -> coalesced 256B gather + coalesced atomic burst.
// ---------------------------------------------------------------------------
__global__ __launch_bounds__(256) void scatter_feats(const float* __restrict__ feat,
                                                     const int* __restrict__ src,
                                                     const int* __restrict__ dst,
                                                     float* __restrict__ msg) {
    long long t = (long long)blockIdx.x * blockDim.x + threadIdx.x;
    int e = (int)(t >> 6);
    int f = (int)(t & 63);
    if (e < N_EDGES) {
        int s = src[e];   // same addr across the wave -> broadcast load
        int d = dst[e];
        float v = feat[(long long)s * D + f];
        atomicAdd(&msg[(long long)d * D + f], v);
    }
}

// ---------------------------------------------------------------------------
// Kernel 3: fused SAGE layer: out = act(mean @ Wl^T + x @ Wr^T + b)
// 4 nodes per 256-thread block; thread (node_local, o) computes one output.
// Weights staged transposed in padded LDS (lanes vary o -> conflict-free).
// Node rows staged in LDS (same addr across wave -> broadcast).
// ---------------------------------------------------------------------------
__global__ __launch_bounds__(256) void sage_layer(const float* __restrict__ self_feat,
                                                  const float* __restrict__ msg,
                                                  const float* __restrict__ cnt,
                                                  const float* __restrict__ Wl,
                                                  const float* __restrict__ Wr,
                                                  const float* __restrict__ bias,
                                                  float* __restrict__ out,
                                                  int relu) {
    __shared__ float sWl[D][D + 1];   // sWl[k][o] = Wl[o][k]
    __shared__ float sWr[D][D + 1];
    __shared__ float srow[4][2][D];   // [node_local][self/mean][k]

    for (int i = threadIdx.x; i < D * D; i += 256) {
        int o = i >> 6, k = i & 63;
        sWl[k][o] = Wl[i];
        sWr[k][o] = Wr[i];
    }

    int nl = threadIdx.x >> 6;
    int o = threadIdx.x & 63;
    int node = blockIdx.x * 4 + nl;

    if (node < N_NODES) {
        float inv = 1.0f / fmaxf(cnt[node], 1.0f);
        srow[nl][0][o] = self_feat[(long long)node * D + o];
        srow[nl][1][o] = msg[(long long)node * D + o] * inv;
    }
    __syncthreads();
    if (node >= N_NODES) return;

    float acc = bias[o];
#pragma unroll
    for (int k = 0; k < D; ++k) {
        acc = fmaf(srow[nl][1][k], sWl[k][o], acc);  // mean @ Wl^T
        acc = fmaf(srow[nl][0][k], sWr[k][o], acc);  // x    @ Wr^T
    }
    if (relu) acc = fmaxf(acc, 0.0f);
    out[(long long)node * D + o] = acc;
}

// ---------------------------------------------------------------------------
// Kernel 4: output projection: out = h @ W_out^T + b_out   [N, 10]
// 64 nodes per block; rows staged in padded LDS.
// ---------------------------------------------------------------------------
__global__ __launch_bounds__(256) void out_layer(const float* __restrict__ h,
                                                 const float* __restrict__ Wout,
                                                 const float* __restrict__ bout,
                                                 float* __restrict__ out) {
    __shared__ float sW[NCLS][D + 1];
    __shared__ float sh[64][D + 1];

    for (int i = threadIdx.x; i < NCLS * D; i += 256) {
        sW[i / D][i % D] = Wout[i];
    }
    int n0 = blockIdx.x * 64;
    for (int i = threadIdx.x; i < 64 * D; i += 256) {
        int nl = i >> 6, k = i & 63;
        int node = n0 + nl;
        sh[nl][k] = (node < N_NODES) ? h[(long long)node * D + k] : 0.0f;
    }
    __syncthreads();

    for (int oi = threadIdx.x; oi < 64 * NCLS; oi += 256) {
        int nl = oi / NCLS, c = oi % NCLS;
        int node = n0 + nl;
        if (node >= N_NODES) continue;
        float acc = bout[c];
#pragma unroll
        for (int k = 0; k < D; ++k) acc = fmaf(sh[nl][k], sW[c][k], acc);
        out[(long long)node * NCLS + c] = acc;
    }
}

// ---------------------------------------------------------------------------
extern "C" void kernel_launch(void* const* d_in, const int* in_sizes, int n_in,
                              void* d_out, int out_size, void* d_ws, size_t ws_size,
                              hipStream_t stream) {
    const float* x   = (const float*)d_in[0];
    const int*   ei  = (const int*)d_in[1];   // [2, N_EDGES]; JAX x64-off -> int32
    const int*   src = ei;
    const int*   dst = ei + N_EDGES;
    const float* W1l = (const float*)d_in[2];
    const float* W1r = (const float*)d_in[3];
    const float* b1  = (const float*)d_in[4];
    const float* W2l = (const float*)d_in[5];
    const float* W2r = (const float*)d_in[6];
    const float* b2  = (const float*)d_in[7];
    const float* Wo  = (const float*)d_in[8];
    const float* bo  = (const float*)d_in[9];
    float* out = (float*)d_out;

    char* ws = (char*)d_ws;
    float* cnt = (float*)ws;                                   // 400 KB slot
    float* msg = (float*)(ws + (1 << 19));                     // 25.6 MB
    float* h1  = (float*)(ws + (1 << 19) + (size_t)FEAT_BYTES);
    float* h2  = (float*)(ws + (1 << 19) + 2 * (size_t)FEAT_BYTES);

    const int scatter_blocks = (int)(((long long)N_EDGES * 64 + 255) / 256);  // 250000
    const int sage_blocks = (N_NODES + 3) / 4;                                // 25000
    const int out_blocks = (N_NODES + 63) / 64;                               // 1563

    // degree counts (same graph for both layers)
    hipMemsetAsync(cnt, 0, N_NODES * sizeof(float), stream);
    count_edges<<<(N_EDGES + 255) / 256, 256, 0, stream>>>(dst, cnt);

    // layer 1
    hipMemsetAsync(msg, 0, (size_t)FEAT_BYTES, stream);
    scatter_feats<<<scatter_blocks, 256, 0, stream>>>(x, src, dst, msg);
    sage_layer<<<sage_blocks, 256, 0, stream>>>(x, msg, cnt, W1l, W1r, b1, h1, 1);

    // layer 2
    hipMemsetAsync(msg, 0, (size_t)FEAT_BYTES, stream);
    scatter_feats<<<scatter_blocks, 256, 0, stream>>>(h1, src, dst, msg);
    sage_layer<<<sage_blocks, 256, 0, stream>>>(h1, msg, cnt, W2l, W2r, b2, h2, 1);

    // output projection
    out_layer<<<out_blocks, 256, 0, stream>>>(h2, Wo, bo, out);
}

// Round 2
// 394.779 us; speedup vs baseline: 1.8493x; 1.8493x over previous
//
#include <hip/hip_runtime.h>

#define N_NODES 100000
#define N_EDGES 1000000
#define D 64
#define NCLS 10

#define SCAN_BLOCK 256
#define N_SCAN_BLOCKS ((N_NODES + SCAN_BLOCK - 1) / SCAN_BLOCK)  // 391

#define NPW 8                 // nodes per wave in fused sage kernel
#define WAVES 4
#define NPB (NPW * WAVES)     // 32 nodes per block

// ---------------------------------------------------------------------------
// CSR build step 1: in-degree counts (int atomics; same graph both layers)
// ---------------------------------------------------------------------------
__global__ __launch_bounds__(256) void count_edges(const int* __restrict__ dst,
                                                   int* __restrict__ cnt) {
    int e = blockIdx.x * blockDim.x + threadIdx.x;
    if (e < N_EDGES) atomicAdd(&cnt[dst[e]], 1);
}

// CSR step 2a: per-block sums of counts
__global__ __launch_bounds__(256) void scan_partials(const int* __restrict__ cnt,
                                                     int* __restrict__ blockSum) {
    __shared__ int s[256];
    int i = blockIdx.x * 256 + threadIdx.x;
    s[threadIdx.x] = (i < N_NODES) ? cnt[i] : 0;
    __syncthreads();
    for (int st = 128; st > 0; st >>= 1) {
        if (threadIdx.x < st) s[threadIdx.x] += s[threadIdx.x + st];
        __syncthreads();
    }
    if (threadIdx.x == 0) blockSum[blockIdx.x] = s[0];
}

// CSR step 2b: exclusive scan of the 391 block sums (single block)
__global__ __launch_bounds__(512) void scan_offsets(const int* __restrict__ blockSum,
                                                    int* __restrict__ blockOff) {
    __shared__ int s[512];
    int t = threadIdx.x;
    int v = (t < N_SCAN_BLOCKS) ? blockSum[t] : 0;
    s[t] = v;
    __syncthreads();
    for (int st = 1; st < 512; st <<= 1) {
        int u = (t >= st) ? s[t - st] : 0;
        __syncthreads();
        s[t] += u;
        __syncthreads();
    }
    if (t < N_SCAN_BLOCKS) blockOff[t] = s[t] - v;  // exclusive
}

// CSR step 2c: per-element exclusive scan -> row_ptr, cursor
__global__ __launch_bounds__(256) void scan_final(const int* __restrict__ cnt,
                                                  const int* __restrict__ blockOff,
                                                  int* __restrict__ row_ptr,
                                                  int* __restrict__ cursor) {
    __shared__ int s[256];
    int i = blockIdx.x * 256 + threadIdx.x;
    int t = threadIdx.x;
    int v = (i < N_NODES) ? cnt[i] : 0;
    s[t] = v;
    __syncthreads();
    for (int st = 1; st < 256; st <<= 1) {
        int u = (t >= st) ? s[t - st] : 0;
        __syncthreads();
        s[t] += u;
        __syncthreads();
    }
    int excl = s[t] - v + blockOff[blockIdx.x];
    if (i < N_NODES) { row_ptr[i] = excl; cursor[i] = excl; }
    if (i == 0) row_ptr[N_NODES] = N_EDGES;
}

// CSR step 3: permute edge sources into dst-sorted order
__global__ __launch_bounds__(256) void fill_csr(const int* __restrict__ src,
                                                const int* __restrict__ dst,
                                                int* __restrict__ cursor,
                                                int* __restrict__ sorted_src) {
    int e = blockIdx.x * blockDim.x + threadIdx.x;
    if (e < N_EDGES) {
        int p = atomicAdd(&cursor[dst[e]], 1);
        sorted_src[p] = src[e];
    }
}

// ---------------------------------------------------------------------------
// Fused SAGE layer: out = act(mean_{CSR} @ Wl^T + x @ Wr^T + b)
// Wave-per-node gather (lane = feature, coalesced 256B rows, no atomics),
// then per-wave GEMV over 8 nodes sharing each LDS weight read.
// Weight LDS layout is chunk-XOR-swizzled so lane f reads its own row via
// conflict-free ds_read_b128: phys dword = o*64 + ((c ^ (o&15))<<2) + j.
// ---------------------------------------------------------------------------
__global__ __launch_bounds__(256) void sage_fused(const float* __restrict__ feat,
                                                  const int* __restrict__ row_ptr,
                                                  const int* __restrict__ sorted_src,
                                                  const float* __restrict__ Wl,
                                                  const float* __restrict__ Wr,
                                                  const float* __restrict__ bias,
                                                  float* __restrict__ out,
                                                  int relu) {
    __shared__ __align__(16) float sWl[D * D];
    __shared__ __align__(16) float sWr[D * D];
    __shared__ __align__(16) float srow[WAVES][NPW][2][D];  // [wave][node][self/mean][k]

    // stage weights (swizzled), float4 in and out
    for (int i = threadIdx.x; i < D * D / 4; i += 256) {
        int o = i >> 4;          // row
        int c = i & 15;          // logical chunk (4 floats)
        int pc = c ^ (o & 15);   // physical chunk
        float4 v = ((const float4*)Wl)[i];
        *((float4*)&sWl[(o << 6) + (pc << 2)]) = v;
        float4 u = ((const float4*)Wr)[i];
        *((float4*)&sWr[(o << 6) + (pc << 2)]) = u;
    }
    __syncthreads();

    const int w = threadIdx.x >> 6;   // wave id
    const int f = threadIdx.x & 63;   // lane = feature / output index
    const int nodeBase = blockIdx.x * NPB + w * NPW;
    const float bl = bias[f];

    // ---- gather phase: mean + self rows for NPW nodes (wave-private) ----
    for (int r = 0; r < NPW; ++r) {
        int node = nodeBase + r;
        if (node >= N_NODES) break;
        int start = row_ptr[node];
        int end   = row_ptr[node + 1];
        int deg   = end - start;

        float a0 = 0.f, a1 = 0.f, a2 = 0.f, a3 = 0.f;
        for (int base = 0; base < deg; base += 64) {
            int nb = min(64, deg - base);
            int s_lane = (f < nb) ? sorted_src[start + base + f] : 0;
            int j = 0;
            for (; j + 3 < nb; j += 4) {
                int s0 = __shfl(s_lane, j);
                int s1 = __shfl(s_lane, j + 1);
                int s2 = __shfl(s_lane, j + 2);
                int s3 = __shfl(s_lane, j + 3);
                a0 += feat[s0 * D + f];
                a1 += feat[s1 * D + f];
                a2 += feat[s2 * D + f];
                a3 += feat[s3 * D + f];
            }
            for (; j < nb; ++j) a0 += feat[__shfl(s_lane, j) * D + f];
        }
        float inv = 1.0f / fmaxf((float)deg, 1.0f);
        float meanv = (a0 + a1 + a2 + a3) * inv;
        float selfv = feat[node * D + f];
        srow[w][r][0][f] = selfv;
        srow[w][r][1][f] = meanv;
    }
    // same wave wrote srow -> ordering guaranteed by lgkmcnt, no barrier needed

    // ---- GEMV phase: 8 nodes share each weight read ----
    float acc[NPW];
#pragma unroll
    for (int r = 0; r < NPW; ++r) acc[r] = bl;

#pragma unroll 4
    for (int c = 0; c < 16; ++c) {
        const int wi = (f << 6) + ((c ^ (f & 15)) << 2);
        const float4 wl4 = *(const float4*)&sWl[wi];
        const float4 wr4 = *(const float4*)&sWr[wi];
#pragma unroll
        for (int r = 0; r < NPW; ++r) {
            const float4 m4 = *(const float4*)&srow[w][r][1][c << 2];
            const float4 s4 = *(const float4*)&srow[w][r][0][c << 2];
            float a = acc[r];
            a = fmaf(m4.x, wl4.x, a); a = fmaf(m4.y, wl4.y, a);
            a = fmaf(m4.z, wl4.z, a); a = fmaf(m4.w, wl4.w, a);
            a = fmaf(s4.x, wr4.x, a); a = fmaf(s4.y, wr4.y, a);
            a = fmaf(s4.z, wr4.z, a); a = fmaf(s4.w, wr4.w, a);
            acc[r] = a;
        }
    }

#pragma unroll
    for (int r = 0; r < NPW; ++r) {
        int node = nodeBase + r;
        if (node < N_NODES) {
            float v = acc[r];
            if (relu) v = fmaxf(v, 0.0f);
            out[node * D + f] = v;
        }
    }
}

// ---------------------------------------------------------------------------
// Output projection: out = h @ W_out^T + b_out   [N, 10]
// ---------------------------------------------------------------------------
__global__ __launch_bounds__(256) void out_layer(const float* __restrict__ h,
                                                 const float* __restrict__ Wout,
                                                 const float* __restrict__ bout,
                                                 float* __restrict__ out) {
    __shared__ float sW[NCLS][D + 1];
    __shared__ float sh[64][D + 1];

    for (int i = threadIdx.x; i < NCLS * D; i += 256) {
        sW[i / D][i % D] = Wout[i];
    }
    int n0 = blockIdx.x * 64;
    for (int i = threadIdx.x; i < 64 * D; i += 256) {
        int nl = i >> 6, k = i & 63;
        int node = n0 + nl;
        sh[nl][k] = (node < N_NODES) ? h[(long long)node * D + k] : 0.0f;
    }
    __syncthreads();

    for (int oi = threadIdx.x; oi < 64 * NCLS; oi += 256) {
        int nl = oi / NCLS, c = oi % NCLS;
        int node = n0 + nl;
        if (node >= N_NODES) continue;
        float acc = bout[c];
#pragma unroll
        for (int k = 0; k < D; ++k) acc = fmaf(sh[nl][k], sW[c][k], acc);
        out[(long long)node * NCLS + c] = acc;
    }
}

// ---------------------------------------------------------------------------
extern "C" void kernel_launch(void* const* d_in, const int* in_sizes, int n_in,
                              void* d_out, int out_size, void* d_ws, size_t ws_size,
                              hipStream_t stream) {
    const float* x   = (const float*)d_in[0];
    const int*   ei  = (const int*)d_in[1];   // [2, N_EDGES]
    const int*   src = ei;
    const int*   dst = ei + N_EDGES;
    const float* W1l = (const float*)d_in[2];
    const float* W1r = (const float*)d_in[3];
    const float* b1  = (const float*)d_in[4];
    const float* W2l = (const float*)d_in[5];
    const float* W2r = (const float*)d_in[6];
    const float* b2  = (const float*)d_in[7];
    const float* Wo  = (const float*)d_in[8];
    const float* bo  = (const float*)d_in[9];
    float* out = (float*)d_out;

    char* ws = (char*)d_ws;
    int*   cnt        = (int*)(ws + 0x000000);             // 400 KB
    int*   row_ptr    = (int*)(ws + 0x080000);             // 400 KB + 4
    int*   cursor     = (int*)(ws + 0x100000);             // 400 KB
    int*   blockSum   = (int*)(ws + 0x180000);             // 2 KB
    int*   blockOff   = (int*)(ws + 0x182000);             // 2 KB
    int*   sorted_src = (int*)(ws + 0x184000);             // 4 MB
    float* h1         = (float*)(ws + 0x580000);           // 25.6 MB
    float* h2         = (float*)(ws + 0x1E00000);          // 25.6 MB

    const int edge_blocks = (N_EDGES + 255) / 256;   // 3907
    const int sage_blocks = (N_NODES + NPB - 1) / NPB; // 3125
    const int out_blocks  = (N_NODES + 63) / 64;     // 1563

    // ---- CSR build (once; shared by both layers) ----
    hipMemsetAsync(cnt, 0, N_NODES * sizeof(int), stream);
    count_edges<<<edge_blocks, 256, 0, stream>>>(dst, cnt);
    scan_partials<<<N_SCAN_BLOCKS, 256, 0, stream>>>(cnt, blockSum);
    scan_offsets<<<1, 512, 0, stream>>>(blockSum, blockOff);
    scan_final<<<N_SCAN_BLOCKS, 256, 0, stream>>>(cnt, blockOff, row_ptr, cursor);
    fill_csr<<<edge_blocks, 256, 0, stream>>>(src, dst, cursor, sorted_src);

    // ---- layers ----
    sage_fused<<<sage_blocks, 256, 0, stream>>>(x,  row_ptr, sorted_src, W1l, W1r, b1, h1, 1);
    sage_fused<<<sage_blocks, 256, 0, stream>>>(h1, row_ptr, sorted_src, W2l, W2r, b2, h2, 1);
    out_layer<<<out_blocks, 256, 0, stream>>>(h2, Wo, bo, out);
}